// Round 7
// baseline (120.336 us; speedup 1.0000x reference)
//
#include <hip/hip_runtime.h>
#include <hip/hip_bf16.h>

// R6 = DIAGNOSTIC round. R3 structure (fp32 planes, BAND 8, 2px/thread,
// launch_bounds(256,5)) + phase-2 repeated REPS=4 with CSE-proof opaque
// offsets and asm sinks (rule #17). Purpose: (a) dur decomposes into
// phase2 share P=(dur-87.6)/3; (b) kan_main becomes top-5 visible ->
// first real VALUBusy/VGPR/Occupancy/LDS_CONFLICT readings.

#define N_CONVS 8
#define HH 64
#define WW 64
#define HO 62
#define WO 62
#define BAND 8
#define LROWS 10                // BAND + 2
#define PW 66                   // plane row pitch (floats)
#define PLANE (LROWS * PW)      // 660 floats per plane
#define REPS 4

// wf layout: [ky][n][32] floats; chunk = {kx0:10, kx1:10, kx2:10, pad:2},
// each 10 = {bw[n][i], sc*sw[n][i][0..7], 0}, i = ky*3+kx.
__global__ __launch_bounds__(768) void kan_prep(const float* __restrict__ bw,
                                                const float* __restrict__ sw,
                                                const float* __restrict__ sc,
                                                float* __restrict__ wf) {
    const int t   = threadIdx.x;        // 0..767
    const int blk = t >> 5;             // ky*8+n
    const int r   = t & 31;
    const int ky  = blk >> 3, n = blk & 7;
    const int kx  = r / 10, j = r % 10;
    float v = 0.0f;
    if (kx < 3 && j <= 8) {
        const int i = ky * 3 + kx;
        v = (j == 0) ? bw[n * 9 + i]
                     : sw[(n * 9 + i) * 8 + (j - 1)] * sc[n * 9 + i];
    }
    wf[t] = v;
}

__global__ __launch_bounds__(256, 5) void kan_main(
    const float* __restrict__ x,     // [256,64,64]
    const float* __restrict__ grid,  // 12 uniform knots (first row)
    const float* __restrict__ wf,    // folded weights (768 floats)
    float* __restrict__ out)         // [256*8,62,62]
{
    __shared__ __align__(16) float feat[9 * PLANE];   // 23.2 KB

    const int blk  = blockIdx.x;
    const int band = blk & 7;
    const int img  = blk >> 3;
    const int r0   = band * BAND;
    const int nr   = (HO - r0) < BAND  ? (HO - r0) : BAND;    // 8 (band7: 6)
    const int nin  = (HH - r0) < LROWS ? (HH - r0) : LROWS;   // 10 (band7: 8)

    const float g0   = grid[0];
    const float invh = __builtin_amdgcn_rcpf(grid[1] - grid[0]);

    // ---- Phase 1: per-pixel features into fp32 SoA planes ----
    const float* xb = x + (size_t)img * (HH * WW) + (size_t)r0 * WW;
    for (int p = threadIdx.x; p < nin * WW; p += 256) {
        const int r = p >> 6, c = p & 63;
        const float xv = xb[p];

        float* fp = &feat[r * PW + c];
        fp[0] = xv * __builtin_amdgcn_rcpf(1.0f + __expf(-xv));  // silu
#pragma unroll
        for (int j = 1; j < 9; j++) fp[j * PLANE] = 0.0f;

        const float u0 = (xv - g0) * invh;
        const int   m  = (int)floorf(u0);
        if (m >= 0 && m <= 10) {
            const float u  = u0 - (float)m;
            const float um = 1.0f - u;
            const float u2 = u * u, u3 = u2 * u;
            const float N0 = um * um * um * (1.0f / 6.0f);
            const float N1 = (3.0f * u3 - 6.0f * u2 + 4.0f) * (1.0f / 6.0f);
            const float N2 = (-3.0f * u3 + 3.0f * u2 + 3.0f * u + 1.0f) * (1.0f / 6.0f);
            const float N3 = u3 * (1.0f / 6.0f);
            const float Nv[4] = {N0, N1, N2, N3};
            // B_j nonzero for j = m-3..m (within 0..7); B_{m-3+s} = Nv[s]
#pragma unroll
            for (int s = 0; s < 4; s++) {
                const int j = m - 3 + s;
                if (j >= 0 && j <= 7) fp[(j + 1) * PLANE] = Nv[s];
            }
        }
    }
    __syncthreads();

    // ---- Phase 2 (x REPS for diagnosis): 2 cols x 8 convs per thread ----
    const int row = threadIdx.x >> 5;          // 0..7
    const int xs  = (threadIdx.x & 31) << 1;   // 0,2,..,62
    if (row < nr && xs < WO) {
        float acc[N_CONVS][2];

#pragma unroll 1
        for (int rep = 0; rep < REPS; ++rep) {
            // Opaque (runtime-zero, uniform, unfoldable, rep-distinct)
            // offsets defeat load/FMA CSE across reps without changing the
            // memory-op structure (blockIdx.x < 2048 << 1<<20).
            const unsigned foff = (blockIdx.x >> 20) * (13u + rep);
            const unsigned woff = (blockIdx.x >> 20) * (7u + rep);

#pragma unroll
            for (int n = 0; n < N_CONVS; n++) { acc[n][0] = 0.0f; acc[n][1] = 0.0f; }

#pragma unroll 1
            for (int ky = 0; ky < 3; ky++) {
                float fw[9][4];
#pragma unroll
                for (int j = 0; j < 9; j++) {
                    const float* pl = &feat[foff + j * PLANE + (row + ky) * PW + xs];
                    const float2 a = *(const float2*)pl;       // ds_read_b64
                    const float2 b = *(const float2*)(pl + 2);
                    fw[j][0] = a.x; fw[j][1] = a.y; fw[j][2] = b.x; fw[j][3] = b.y;
                }
                const float* wk = wf + woff + (ky << 8);       // uniform -> s_load
#pragma unroll
                for (int n = 0; n < N_CONVS; n++) {
                    const float* wn = wk + (n << 5);
#pragma unroll
                    for (int kx = 0; kx < 3; kx++) {
                        const float* gg = wn + kx * 10;
#pragma unroll
                        for (int t = 0; t < 2; t++) {
                            float a = acc[n][t];
#pragma unroll
                            for (int j = 0; j < 9; j++)
                                a = fmaf(gg[j], fw[j][kx + t], a);
                            acc[n][t] = a;
                        }
                    }
                }
            }
            // Keep this rep's results live (prevents DCE of reps 0..2).
#pragma unroll
            for (int n = 0; n < N_CONVS; n++)
                asm volatile("" :: "v"(acc[n][0]), "v"(acc[n][1]));
        }

        const int oy = r0 + row;
        float* ob = out + (size_t)img * N_CONVS * (HO * WO) + oy * WO + xs;
#pragma unroll
        for (int n = 0; n < N_CONVS; n++)
            *(float2*)(ob + n * (HO * WO)) = make_float2(acc[n][0], acc[n][1]);
    }
}

extern "C" void kernel_launch(void* const* d_in, const int* in_sizes, int n_in,
                              void* d_out, int out_size, void* d_ws, size_t ws_size,
                              hipStream_t stream) {
    const float* x    = (const float*)d_in[0];
    const float* bw   = (const float*)d_in[1];
    const float* sw   = (const float*)d_in[2];
    const float* sc   = (const float*)d_in[3];
    const float* grid = (const float*)d_in[4];
    float* out = (float*)d_out;
    float* wf  = (float*)d_ws;

    kan_prep<<<1, 768, 0, stream>>>(bw, sw, sc, wf);
    kan_main<<<256 * 8, 256, 0, stream>>>(x, grid, wf, out);
}

// Round 10
// 112.680 us; speedup vs baseline: 1.0679x; 1.0679x over previous
//
#include <hip/hip_runtime.h>
#include <hip/hip_bf16.h>

// KAN conv: 8x KANLinear(9->1) over 3x3 patches, 256 images of 64x64.
// R9 = R7 resubmit (two container failures, never benched; code audited
// for OOB/hang — clean).
// Single kernel (prep folded algebraically into phase 2: the spline
// dot uses raw sw rows + sc/bw applied after), and phase 1 software-
// pipelined: all 2-3 pixel loads issued upfront (fixed-trip structure),
// one waitcnt, then feature compute -> LDS. launch_bounds(256,6).
// R6 diagnosis: phase2 ~11us (~80% of FMA floor), phase1+prep+convoy ~20us.

#define N_CONVS 8
#define HH 64
#define WW 64
#define HO 62
#define WO 62
#define BAND 8
#define LROWS 10                // BAND + 2
#define PW 66                   // plane row pitch (floats)
#define PLANE (LROWS * PW)      // 660 floats per plane

__device__ __forceinline__ void compute_features(float xv, float g0, float invh,
                                                 float* fp) {
    fp[0] = xv * __builtin_amdgcn_rcpf(1.0f + __expf(-xv));  // silu
#pragma unroll
    for (int j = 1; j < 9; j++) fp[j * PLANE] = 0.0f;

    const float u0 = (xv - g0) * invh;
    const int   m  = (int)floorf(u0);
    if (m >= 0 && m <= 10) {
        const float u  = u0 - (float)m;
        const float um = 1.0f - u;
        const float u2 = u * u, u3 = u2 * u;
        const float N0 = um * um * um * (1.0f / 6.0f);
        const float N1 = (3.0f * u3 - 6.0f * u2 + 4.0f) * (1.0f / 6.0f);
        const float N2 = (-3.0f * u3 + 3.0f * u2 + 3.0f * u + 1.0f) * (1.0f / 6.0f);
        const float N3 = u3 * (1.0f / 6.0f);
        const float Nv[4] = {N0, N1, N2, N3};
        // B_j nonzero for j = m-3..m (within 0..7); B_{m-3+s} = Nv[s]
#pragma unroll
        for (int s = 0; s < 4; s++) {
            const int j = m - 3 + s;
            if (j >= 0 && j <= 7) fp[(j + 1) * PLANE] = Nv[s];
        }
    }
}

__global__ __launch_bounds__(256, 6) void kan_main(
    const float* __restrict__ x,     // [256,64,64]
    const float* __restrict__ bw,    // [8][9]
    const float* __restrict__ sw,    // [8][9][8]
    const float* __restrict__ sc,    // [8][9]
    const float* __restrict__ grid,  // 12 uniform knots (first row)
    float* __restrict__ out)         // [256*8,62,62]
{
    __shared__ __align__(16) float feat[9 * PLANE];   // 23.2 KB

    const int blk  = blockIdx.x;
    const int band = blk & 7;
    const int img  = blk >> 3;
    const int r0   = band * BAND;
    const int nr   = (HO - r0) < BAND  ? (HO - r0) : BAND;    // 8 (band7: 6)
    const int nin  = (HH - r0) < LROWS ? (HH - r0) : LROWS;   // 10 (band7: 8)
    const int npix = nin * WW;                                // 640 / 512

    const float g0   = grid[0];
    const float invh = __builtin_amdgcn_rcpf(grid[1] - grid[0]);

    // ---- Phase 1: pipelined loads (all issued before any use) ----
    const int t = threadIdx.x;
    const float* xb = x + (size_t)img * (HH * WW) + (size_t)r0 * WW;
    const float xv0 = xb[t];
    const float xv1 = xb[t + 256];
    const bool  has2 = (t + 512 < npix);
    float xv2 = 0.0f;
    if (has2) xv2 = xb[t + 512];

    compute_features(xv0, g0, invh, &feat[(t >> 6) * PW + (t & 63)]);
    {
        const int p = t + 256;
        compute_features(xv1, g0, invh, &feat[(p >> 6) * PW + (p & 63)]);
    }
    if (has2) {
        const int p = t + 512;
        compute_features(xv2, g0, invh, &feat[(p >> 6) * PW + (p & 63)]);
    }
    __syncthreads();

    // ---- Phase 2: 2 consecutive output cols x 8 convs per thread ----
    // acc[n] += sc[n,i] * (sum_j sw[n,i,j]*B_j) + bw[n,i]*silu, i=ky*3+kx
    const int row = threadIdx.x >> 5;          // 0..7
    const int xs  = (threadIdx.x & 31) << 1;   // 0,2,..,62

    float acc[N_CONVS][2];
#pragma unroll
    for (int n = 0; n < N_CONVS; n++) { acc[n][0] = 0.0f; acc[n][1] = 0.0f; }

#pragma unroll 1
    for (int ky = 0; ky < 3; ky++) {
        float fw[9][4];
#pragma unroll
        for (int j = 0; j < 9; j++) {
            const float* pl = &feat[j * PLANE + (row + ky) * PW + xs];
            const float2 a = *(const float2*)pl;       // ds_read_b64
            const float2 b = *(const float2*)(pl + 2);
            fw[j][0] = a.x; fw[j][1] = a.y; fw[j][2] = b.x; fw[j][3] = b.y;
        }
#pragma unroll
        for (int n = 0; n < N_CONVS; n++) {
            const float* swp = sw + (n * 9 + ky * 3) * 8;  // 24 contiguous
            const float* bwp = bw + n * 9 + ky * 3;        // 3 contiguous
            const float* scp = sc + n * 9 + ky * 3;        // 3 contiguous
#pragma unroll
            for (int kx = 0; kx < 3; kx++) {
                float s0 = 0.0f, s1 = 0.0f;
#pragma unroll
                for (int j = 0; j < 8; j++) {
                    const float w = swp[kx * 8 + j];
                    s0 = fmaf(w, fw[j + 1][kx],     s0);
                    s1 = fmaf(w, fw[j + 1][kx + 1], s1);
                }
                acc[n][0] = fmaf(scp[kx], s0, acc[n][0]);
                acc[n][1] = fmaf(scp[kx], s1, acc[n][1]);
                acc[n][0] = fmaf(bwp[kx], fw[0][kx],     acc[n][0]);
                acc[n][1] = fmaf(bwp[kx], fw[0][kx + 1], acc[n][1]);
            }
        }
    }

    if (row < nr && xs < WO) {
        const int oy = r0 + row;
        float* ob = out + (size_t)img * N_CONVS * (HO * WO) + oy * WO + xs;
#pragma unroll
        for (int n = 0; n < N_CONVS; n++)
            *(float2*)(ob + n * (HO * WO)) = make_float2(acc[n][0], acc[n][1]);
    }
}

extern "C" void kernel_launch(void* const* d_in, const int* in_sizes, int n_in,
                              void* d_out, int out_size, void* d_ws, size_t ws_size,
                              hipStream_t stream) {
    const float* x    = (const float*)d_in[0];
    const float* bw   = (const float*)d_in[1];
    const float* sw   = (const float*)d_in[2];
    const float* sc   = (const float*)d_in[3];
    const float* grid = (const float*)d_in[4];
    float* out = (float*)d_out;

    kan_main<<<256 * 8, 256, 0, stream>>>(x, bw, sw, sc, grid, out);
}

// Round 11
// 86.102 us; speedup vs baseline: 1.3976x; 1.3087x over previous
//
#include <hip/hip_runtime.h>
#include <hip/hip_bf16.h>

// KAN conv: 8x KANLinear(9->1) over 3x3 patches, 256 images of 64x64.
// R10 = R3 proven structure (87.6us: prep->wf folded weights, BAND 8,
// fp32 planes, launch_bounds(256,5), guarded phase 2) + ONE change:
// phase-1 software pipeline (2-3 loads issued upfront, fixed trip).
// R9 post-mortem: bundling launch_bounds(256,6) + raw-weight reads caused
// scratch spill (WRITE 128MB vs 31.5MB out) and 2x kernel time. Reverted.

#define N_CONVS 8
#define HH 64
#define WW 64
#define HO 62
#define WO 62
#define BAND 8
#define LROWS 10                // BAND + 2
#define PW 66                   // plane row pitch (floats)
#define PLANE (LROWS * PW)      // 660 floats per plane

// wf layout: [ky][n][32] floats; chunk = {kx0:10, kx1:10, kx2:10, pad:2},
// each 10 = {bw[n][i], sc*sw[n][i][0..7], 0}, i = ky*3+kx.
__global__ __launch_bounds__(768) void kan_prep(const float* __restrict__ bw,
                                                const float* __restrict__ sw,
                                                const float* __restrict__ sc,
                                                float* __restrict__ wf) {
    const int t   = threadIdx.x;        // 0..767
    const int blk = t >> 5;             // ky*8+n
    const int r   = t & 31;
    const int ky  = blk >> 3, n = blk & 7;
    const int kx  = r / 10, j = r % 10;
    float v = 0.0f;
    if (kx < 3 && j <= 8) {
        const int i = ky * 3 + kx;
        v = (j == 0) ? bw[n * 9 + i]
                     : sw[(n * 9 + i) * 8 + (j - 1)] * sc[n * 9 + i];
    }
    wf[t] = v;
}

__device__ __forceinline__ void compute_features(float xv, float g0, float invh,
                                                 float* fp) {
    fp[0] = xv * __builtin_amdgcn_rcpf(1.0f + __expf(-xv));  // silu
#pragma unroll
    for (int j = 1; j < 9; j++) fp[j * PLANE] = 0.0f;

    const float u0 = (xv - g0) * invh;
    const int   m  = (int)floorf(u0);
    if (m >= 0 && m <= 10) {
        const float u  = u0 - (float)m;
        const float um = 1.0f - u;
        const float u2 = u * u, u3 = u2 * u;
        const float N0 = um * um * um * (1.0f / 6.0f);
        const float N1 = (3.0f * u3 - 6.0f * u2 + 4.0f) * (1.0f / 6.0f);
        const float N2 = (-3.0f * u3 + 3.0f * u2 + 3.0f * u + 1.0f) * (1.0f / 6.0f);
        const float N3 = u3 * (1.0f / 6.0f);
        const float Nv[4] = {N0, N1, N2, N3};
        // B_j nonzero for j = m-3..m (within 0..7); B_{m-3+s} = Nv[s]
#pragma unroll
        for (int s = 0; s < 4; s++) {
            const int j = m - 3 + s;
            if (j >= 0 && j <= 7) fp[(j + 1) * PLANE] = Nv[s];
        }
    }
}

__global__ __launch_bounds__(256, 5) void kan_main(
    const float* __restrict__ x,     // [256,64,64]
    const float* __restrict__ grid,  // 12 uniform knots (first row)
    const float* __restrict__ wf,    // folded weights (768 floats)
    float* __restrict__ out)         // [256*8,62,62]
{
    __shared__ __align__(16) float feat[9 * PLANE];   // 23.2 KB

    const int blk  = blockIdx.x;
    const int band = blk & 7;
    const int img  = blk >> 3;
    const int r0   = band * BAND;
    const int nr   = (HO - r0) < BAND  ? (HO - r0) : BAND;    // 8 (band7: 6)
    const int nin  = (HH - r0) < LROWS ? (HH - r0) : LROWS;   // 10 (band7: 8)
    const int npix = nin * WW;                                // 640 / 512

    const float g0   = grid[0];
    const float invh = __builtin_amdgcn_rcpf(grid[1] - grid[0]);

    // ---- Phase 1: pipelined loads (issued before any use), then features ----
    const int t = threadIdx.x;
    const float* xb = x + (size_t)img * (HH * WW) + (size_t)r0 * WW;
    const float xv0 = xb[t];
    const float xv1 = xb[t + 256];          // npix >= 512 always
    const bool  has2 = (t + 512 < npix);
    float xv2 = 0.0f;
    if (has2) xv2 = xb[t + 512];

    compute_features(xv0, g0, invh, &feat[(t >> 6) * PW + (t & 63)]);
    {
        const int p = t + 256;
        compute_features(xv1, g0, invh, &feat[(p >> 6) * PW + (p & 63)]);
    }
    if (has2) {
        const int p = t + 512;
        compute_features(xv2, g0, invh, &feat[(p >> 6) * PW + (p & 63)]);
    }
    __syncthreads();

    // ---- Phase 2: 2 consecutive output cols x 8 convs per thread ----
    const int row = threadIdx.x >> 5;          // 0..7
    const int xs  = (threadIdx.x & 31) << 1;   // 0,2,..,62
    if (row < nr && xs < WO) {
        float acc[N_CONVS][2];
#pragma unroll
        for (int n = 0; n < N_CONVS; n++) { acc[n][0] = 0.0f; acc[n][1] = 0.0f; }

#pragma unroll 1
        for (int ky = 0; ky < 3; ky++) {
            float fw[9][4];
#pragma unroll
            for (int j = 0; j < 9; j++) {
                const float* pl = &feat[j * PLANE + (row + ky) * PW + xs];
                const float2 a = *(const float2*)pl;       // ds_read_b64
                const float2 b = *(const float2*)(pl + 2);
                fw[j][0] = a.x; fw[j][1] = a.y; fw[j][2] = b.x; fw[j][3] = b.y;
            }
            const float* wk = wf + (ky << 8);              // uniform -> s_load
#pragma unroll
            for (int n = 0; n < N_CONVS; n++) {
                const float* wn = wk + (n << 5);
#pragma unroll
                for (int kx = 0; kx < 3; kx++) {
                    const float* gg = wn + kx * 10;
#pragma unroll
                    for (int tt = 0; tt < 2; tt++) {
                        float a = acc[n][tt];
#pragma unroll
                        for (int j = 0; j < 9; j++)
                            a = fmaf(gg[j], fw[j][kx + tt], a);
                        acc[n][tt] = a;
                    }
                }
            }
        }

        const int oy = r0 + row;
        float* ob = out + (size_t)img * N_CONVS * (HO * WO) + oy * WO + xs;
#pragma unroll
        for (int n = 0; n < N_CONVS; n++)
            *(float2*)(ob + n * (HO * WO)) = make_float2(acc[n][0], acc[n][1]);
    }
}

extern "C" void kernel_launch(void* const* d_in, const int* in_sizes, int n_in,
                              void* d_out, int out_size, void* d_ws, size_t ws_size,
                              hipStream_t stream) {
    const float* x    = (const float*)d_in[0];
    const float* bw   = (const float*)d_in[1];
    const float* sw   = (const float*)d_in[2];
    const float* sc   = (const float*)d_in[3];
    const float* grid = (const float*)d_in[4];
    float* out = (float*)d_out;
    float* wf  = (float*)d_ws;

    kan_prep<<<1, 768, 0, stream>>>(bw, sw, sc, wf);
    kan_main<<<256 * 8, 256, 0, stream>>>(x, grid, wf, out);
}